// Round 15
// baseline (323.533 us; speedup 1.0000x reference)
//
#include <hip/hip_runtime.h>
#include <hip/hip_bf16.h>

// Problem constants
#define EMBED    256
#define HIDDEN   512
#define VOCAB    10000
#define WFC_PAD  10112   // 79 * 128, zero-padded rows for gload_lds edge tiles
#define NTILES   79      // WFC_PAD / 128
#define FEAT_DIM 1024
#define BATCH    128
#define NREGS    49
#define TSTEPS   32      // CAPLEN-1

typedef unsigned short u16;
typedef unsigned long long u64;
using f32x4 = __attribute__((ext_vector_type(4))) float;
using s16x8 = __attribute__((ext_vector_type(8))) short;
using u32x4 = __attribute__((ext_vector_type(4))) unsigned;

__device__ __forceinline__ u16 f2bf(float f) {
  __hip_bfloat16 h = __float2bfloat16(f);
  return *reinterpret_cast<u16*>(&h);
}
__device__ __forceinline__ float sig_(float x) {
  return 1.0f / (1.0f + __expf(-x));
}
__device__ __forceinline__ float tanh_(float x) {
  x = fminf(fmaxf(x, -15.f), 15.f);
  float e = __expf(2.f * x);
  return (e - 1.f) / (e + 1.f);
}
// async global->LDS, 16B per lane; LDS dest is wave-uniform base + lane*16
__device__ __forceinline__ void gl_lds16(const u16* g, u16* l) {
  __builtin_amdgcn_global_load_lds(
      (const __attribute__((address_space(1))) unsigned*)g,
      (__attribute__((address_space(3))) unsigned*)l, 16, 0, 0);
}

struct GatePtrs {
  const float* W[4];
  const float* U[4];
  const float* b[4];
};

// ---------------------------------------------------------------------------
// Kernel 1 (merged prep): blocks 0..127 = feats_bf; 128..639 = W/U transpose
// +cast; 640..1663 = X_emb gather (independent of feats now); 1664.. = Wfc
// cast (padded) + bcat.
// ---------------------------------------------------------------------------
__global__ __launch_bounds__(256)
void k_prep_all(GatePtrs p, const float* __restrict__ features,
                const float* __restrict__ W_ft, const float* __restrict__ b_ft,
                const float* __restrict__ W_fc, const float* __restrict__ emb,
                const int* __restrict__ captions,
                u16* __restrict__ feats_bf, u16* __restrict__ WcatT,
                u16* __restrict__ UcatT, float* __restrict__ bcat,
                u16* __restrict__ Wfc_bf, u16* __restrict__ X_emb) {
  __shared__ float sh[64 * 65];
  int bid = blockIdx.x, tid = threadIdx.x;

  if (bid < 128) {
    // ---- feats: mean over regions, project, cast to bf16 ----
    float* mean = sh;
    int b = bid;
    const float* fb = features + (size_t)b * NREGS * FEAT_DIM;
    for (int d = tid; d < FEAT_DIM; d += 256) {
      float s = 0.f;
      for (int r = 0; r < NREGS; ++r) s += fb[r * FEAT_DIM + d];
      mean[d] = s * (1.0f / 49.0f);
    }
    __syncthreads();
    const float* w = W_ft + (size_t)tid * FEAT_DIM;
    float acc = b_ft[tid];
#pragma unroll 4
    for (int d = 0; d < FEAT_DIM; d += 4) {
      float4 m4 = *(const float4*)&mean[d];
      float4 w4 = *(const float4*)&w[d];
      acc += m4.x * w4.x + m4.y * w4.y + m4.z * w4.z + m4.w * w4.w;
    }
    feats_bf[b * EMBED + tid] = f2bf(acc);
  } else if (bid < 640) {
    // ---- W/U transpose + cast ----
    int idx = bid - 128;
    int z = idx >> 8;
    int rem = idx & 255;
    int g = rem >> 6;
    int x = rem & 63;
    float (*tile)[65] = (float(*)[65])sh;
    const float* src = z ? p.U[g] : p.W[g];
    u16* dst = z ? UcatT : WcatT;
    int tj = (x & 7) * 64;
    int tk = (x >> 3) * 64;
    int tx = tid & 63, ty = tid >> 6;
#pragma unroll
    for (int i = 0; i < 16; ++i)
      tile[ty + 4 * i][tx] = src[(size_t)(tk + ty + 4 * i) * HIDDEN + tj + tx];
    __syncthreads();
#pragma unroll
    for (int i = 0; i < 16; ++i)
      dst[(size_t)(g * 512 + tj + ty + 4 * i) * 512 + tk + tx] = f2bf(tile[tx][ty + 4 * i]);
  } else if (bid < 1664) {
    // ---- X_emb gather: row r = t*128+b -> emb[captions[b][t]][0..255] ----
    int idx = (bid - 640) * 256 + tid;   // [0, 4096*64)
    int r = idx >> 6, c4 = (idx & 63) * 4;
    int t = r >> 7, b = r & 127;
    int tok = captions[b * 33 + t];
    float4 v = *(const float4*)(emb + (size_t)tok * EMBED + c4);
    ushort4 o;
    o.x = f2bf(v.x); o.y = f2bf(v.y); o.z = f2bf(v.z); o.w = f2bf(v.w);
    *(ushort4*)(X_emb + (size_t)r * EMBED + c4) = o;
  } else {
    // ---- Wfc cast (zero-padded) + bcat ----
    int idx = (bid - 1664) * 256 + tid;
    if (idx < WFC_PAD * HIDDEN / 4) {
      size_t e0 = (size_t)idx * 4;
      ushort4 o;
      if (e0 < (size_t)VOCAB * HIDDEN) {
        float4 v = *(const float4*)(W_fc + e0);
        o.x = f2bf(v.x); o.y = f2bf(v.y); o.z = f2bf(v.z); o.w = f2bf(v.w);
      } else {
        o.x = o.y = o.z = o.w = 0;
      }
      *(ushort4*)(Wfc_bf + e0) = o;
    }
    if (idx < 4 * HIDDEN) bcat[idx] = p.b[idx >> 9][idx & 511];
  }
}

// ---------------------------------------------------------------------------
// Kernel 2: bf16 GEMM, generalized m97 structure:
// C[M][N] = A[M][K](lda) @ Bt[N][K](ldb)^T + bias.
// bias1 != null: bias1[n].  bias1 == null: bias2[(m & 127)*N + n] (per-row,
// used to fold the step-invariant feats contribution into gates_pre).
// Caller guarantees M, N multiples of 128 (true for both uses).
// ---------------------------------------------------------------------------
__global__ __launch_bounds__(256)
void k_gemm_bt(const u16* __restrict__ A, int lda,
               const u16* __restrict__ Bt, int ldb,
               const float* __restrict__ bias1, const float* __restrict__ bias2,
               float* __restrict__ C, int M, int N, int K) {
  __shared__ u16 Al[128 * 32];
  __shared__ u16 Bl[128 * 32];
  int tid = threadIdx.x;
  int lane = tid & 63;
  int w = tid >> 6;
  int wr = w & 1, wc = w >> 1;

  // bijective XCD swizzle (m204)
  int Mtiles = gridDim.y, Ntiles = gridDim.x;
  int nwg = Mtiles * Ntiles;
  int id = blockIdx.y * Ntiles + blockIdx.x;
  int q = nwg >> 3, r = nwg & 7;
  int xcd = id & 7, pos = id >> 3;
  int wg = (xcd < r ? xcd * (q + 1) : r * (q + 1) + (xcd - r) * q) + pos;
  int m0 = (wg % Mtiles) * 128;
  int n0 = (wg / Mtiles) * 128;

  f32x4 acc[4][4];
#pragma unroll
  for (int i = 0; i < 4; ++i)
#pragma unroll
    for (int j = 0; j < 4; ++j) acc[i][j] = (f32x4){0.f, 0.f, 0.f, 0.f};

  int srowq = lane >> 2;
  int skq   = (lane & 3) * 8;

  for (int k0 = 0; k0 < K; k0 += 32) {
    __syncthreads();
#pragma unroll
    for (int i = 0; i < 2; ++i) {
      int rr = w * 32 + i * 16;
      gl_lds16(A + (size_t)(m0 + rr + srowq) * lda + k0 + skq, Al + rr * 32);
      gl_lds16(Bt + (size_t)(n0 + rr + srowq) * ldb + k0 + skq, Bl + rr * 32);
    }
    __syncthreads();

    const u16* ab = Al + (wr * 64 + (lane & 15)) * 32 + (lane >> 4) * 8;
    const u16* bb = Bl + (wc * 64 + (lane & 15)) * 32 + (lane >> 4) * 8;
    s16x8 af[4], bf_[4];
#pragma unroll
    for (int mi = 0; mi < 4; ++mi) af[mi] = *(const s16x8*)(ab + mi * 16 * 32);
#pragma unroll
    for (int ni = 0; ni < 4; ++ni) bf_[ni] = *(const s16x8*)(bb + ni * 16 * 32);
#pragma unroll
    for (int mi = 0; mi < 4; ++mi)
#pragma unroll
      for (int ni = 0; ni < 4; ++ni)
        acc[mi][ni] = __builtin_amdgcn_mfma_f32_16x16x32_bf16(af[mi], bf_[ni], acc[mi][ni], 0, 0, 0);
  }

  int rbase = (lane >> 4) * 4;
  int colf = lane & 15;
#pragma unroll
  for (int mi = 0; mi < 4; ++mi) {
    int mbase = m0 + wr * 64 + mi * 16 + rbase;
#pragma unroll
    for (int ni = 0; ni < 4; ++ni) {
      int n = n0 + wc * 64 + ni * 16 + colf;
      if (n < N) {
#pragma unroll
        for (int reg = 0; reg < 4; ++reg) {
          int mm = mbase + reg;
          float bv = bias1 ? bias1[n] : bias2[(size_t)(mm & 127) * N + n];
          C[(size_t)mm * N + n] = acc[mi][ni][reg] + bv;
        }
      }
    }
  }
}

// ---------------------------------------------------------------------------
// Kernel 3 (FUSED — round-13 proven, byte-identical): blocks 0..63 = LSTM
// (block flags, __syncthreads drain, tid0 flag store, gpv prefetch after
// flag); blocks 64..255 = final-GEMM workers (t-major tickets, wave0 poll).
// ---------------------------------------------------------------------------
#define USTR 520

__global__ __launch_bounds__(256, 1)
void k_fused(const u16* __restrict__ UcatT, const float* __restrict__ gates_pre,
             unsigned* __restrict__ hx, int* __restrict__ flags, int* __restrict__ ticket,
             const u16* __restrict__ Wfc, const float* __restrict__ b_fc,
             float* __restrict__ out) {
  __shared__ u16 SH[128 * USTR];   // lstm: Ul (133,120B); workers: Al|Bl (16KB)
  __shared__ int tickLds;
  int tid = threadIdx.x;
  int lane = tid & 63;
  int w = tid >> 6;

  if (blockIdx.x < 64) {
    // ======================= LSTM path =======================
    u16* Ul = SH;
    int wr = w & 1, wj = w >> 1;
    int mg = blockIdx.x >> 4;
    int jb = blockIdx.x & 15;
    int b0 = mg * 32;
    int j0 = jb * 32;

    for (int i = tid; i < 128 * 64; i += 256) {
      int row = i >> 6;
      int kc = (i & 63) * 8;
      int gr = ((row >> 5) << 9) + j0 + (row & 31);
      uint4 v = *(const uint4*)(UcatT + (size_t)gr * 512 + kc);
      *(uint4*)(Ul + row * USTR + kc) = v;
    }
    __syncthreads();

    int jloc = wj * 16 + (lane & 15);
    int jj = j0 + jloc;
    int rb = wr * 16 + (lane >> 4) * 4;
    int arow = b0 + wr * 16 + (lane & 15);
    const u16* ubase = Ul + (size_t)jloc * USTR + (lane >> 4) * 8;
    int* myflag = flags + mg * 16 + jb;
    const int* pollp = flags + mg * 16 + (lane & 15);

    float c[4] = {0.f, 0.f, 0.f, 0.f};
    float gpv[16];

#pragma unroll
    for (int reg = 0; reg < 4; ++reg)
#pragma unroll
      for (int gi = 0; gi < 4; ++gi)
        gpv[reg * 4 + gi] = gates_pre[((size_t)(b0 + rb + reg)) * 2048 + gi * 512 + jj];

#pragma unroll 1
    for (int t = 0; t < TSTEPS; ++t) {
      f32x4 acc[4];
#pragma unroll
      for (int gi = 0; gi < 4; ++gi) acc[gi] = (f32x4){0.f, 0.f, 0.f, 0.f};

      if (t > 0) {
        // poll the 16 block-flags of this m-group (one 64B line);
        // first round's vmcnt(0) also drains our gpv prefetch (intended).
        int fv;
        do {
          asm volatile(
              "global_load_dword %0, %1, off sc0 sc1\n\t"
              "s_waitcnt vmcnt(0)"
              : "=v"(fv) : "v"(pollp) : "memory");
        } while (!__all(fv >= t));

        const u16* hp = (const u16*)hx + ((size_t)(t - 1) * 128 + arow) * 512 + (lane >> 4) * 8;
        u32x4 f[16];
        asm volatile(
            "global_load_dwordx4 %0, %4, off sc0 sc1\n\t"
            "global_load_dwordx4 %1, %4, off offset:64 sc0 sc1\n\t"
            "global_load_dwordx4 %2, %4, off offset:128 sc0 sc1\n\t"
            "global_load_dwordx4 %3, %4, off offset:192 sc0 sc1"
            : "=&v"(f[0]), "=&v"(f[1]), "=&v"(f[2]), "=&v"(f[3])
            : "v"(hp) : "memory");
        asm volatile(
            "global_load_dwordx4 %0, %4, off offset:256 sc0 sc1\n\t"
            "global_load_dwordx4 %1, %4, off offset:320 sc0 sc1\n\t"
            "global_load_dwordx4 %2, %4, off offset:384 sc0 sc1\n\t"
            "global_load_dwordx4 %3, %4, off offset:448 sc0 sc1"
            : "=&v"(f[4]), "=&v"(f[5]), "=&v"(f[6]), "=&v"(f[7])
            : "v"(hp) : "memory");
        asm volatile(
            "global_load_dwordx4 %0, %4, off offset:512 sc0 sc1\n\t"
            "global_load_dwordx4 %1, %4, off offset:576 sc0 sc1\n\t"
            "global_load_dwordx4 %2, %4, off offset:640 sc0 sc1\n\t"
            "global_load_dwordx4 %3, %4, off offset:704 sc0 sc1"
            : "=&v"(f[8]), "=&v"(f[9]), "=&v"(f[10]), "=&v"(f[11])
            : "v"(hp) : "memory");
        asm volatile(
            "global_load_dwordx4 %0, %4, off offset:768 sc0 sc1\n\t"
            "global_load_dwordx4 %1, %4, off offset:832 sc0 sc1\n\t"
            "global_load_dwordx4 %2, %4, off offset:896 sc0 sc1\n\t"
            "global_load_dwordx4 %3, %4, off offset:960 sc0 sc1\n\t"
            "s_waitcnt vmcnt(0)"
            : "=&v"(f[12]), "=&v"(f[13]), "=&v"(f[14]), "=&v"(f[15])
            : "v"(hp) : "memory");
        __builtin_amdgcn_sched_barrier(0);

#pragma unroll
        for (int kk = 0; kk < 16; ++kk) {
          s16x8 af = __builtin_bit_cast(s16x8, f[kk]);
#pragma unroll
          for (int gi = 0; gi < 4; ++gi) {
            s16x8 bf_ = *(const s16x8*)(ubase + (size_t)gi * 32 * USTR + kk * 32);
            acc[gi] = __builtin_amdgcn_mfma_f32_16x16x32_bf16(af, bf_, acc[gi], 0, 0, 0);
          }
        }
      }

      // cell epilogue (registers), publish h
#pragma unroll
      for (int reg = 0; reg < 4; ++reg) {
        float pi = acc[0][reg] + gpv[reg * 4 + 0];
        float pf = acc[1][reg] + gpv[reg * 4 + 1];
        float pg = acc[2][reg] + gpv[reg * 4 + 2];
        float po = acc[3][reg] + gpv[reg * 4 + 3];
        float iv = sig_(pi), fv2 = sig_(pf), gv = tanh_(pg), ov = sig_(po);
        float cn = fv2 * c[reg] + iv * gv;
        c[reg] = cn;
        float hn = ov * tanh_(cn);
        u16 hb = f2bf(hn);
        unsigned pv = hb;
        unsigned nv = __shfl_down(pv, 1);
        if ((lane & 1) == 0) {
          unsigned packed = pv | (nv << 16);
          unsigned* dst = hx + ((size_t)t * 128 + b0 + rb + reg) * 256 + (jj >> 1);
          asm volatile("global_store_dword %0, %1, off sc0 sc1"
                       :: "v"(dst), "v"(packed) : "memory");
        }
      }

      // barrier drains all waves' h stores -> tid0 publishes the block flag
      __syncthreads();
      if (tid == 0) {
        int fl = t + 1;
        asm volatile("global_store_dword %0, %1, off sc0 sc1"
                     :: "v"(myflag), "v"(fl) : "memory");
      }

      // gpv prefetch AFTER the flag — off the inter-block critical path;
      // its latency is absorbed by the next poll round's vmcnt(0).
      if (t < TSTEPS - 1) {
#pragma unroll
        for (int reg = 0; reg < 4; ++reg)
#pragma unroll
          for (int gi = 0; gi < 4; ++gi)
            gpv[reg * 4 + gi] =
                gates_pre[((size_t)(t + 1) * 128 + b0 + rb + reg) * 2048 + gi * 512 + jj];
      }
    }
  } else {
    // ======================= GEMM worker path =======================
    u16* Al = SH;
    u16* Bl = SH + 128 * 32;
    int wr = w & 1, wc = w >> 1;
    int srowq = lane >> 2;
    int skq   = (lane & 3) * 8;
    const u16* hx16 = (const u16*)hx;

    for (;;) {
      if (tid == 0)
        tickLds = __hip_atomic_fetch_add(ticket, 1, __ATOMIC_RELAXED, __HIP_MEMORY_SCOPE_AGENT);
      __syncthreads();
      int T = tickLds;
      if (T >= TSTEPS * NTILES) break;
      int t = T / NTILES, nt = T % NTILES;

      // gate: all 64 step-flags >= t+1 — only wave 0 polls, barrier broadcasts
      if (w == 0) {
        const int* fp = flags + lane;
        for (;;) {
          int fv;
          asm volatile(
              "global_load_dword %0, %1, off sc0 sc1\n\t"
              "s_waitcnt vmcnt(0)"
              : "=v"(fv) : "v"(fp) : "memory");
          if (__all(fv >= t + 1)) break;
          __builtin_amdgcn_s_sleep(64);
        }
      }
      __syncthreads();

      const u16* A = hx16 + (size_t)t * 128 * 512;
      int n0 = nt * 128;

      f32x4 acc[4][4];
#pragma unroll
      for (int i = 0; i < 4; ++i)
#pragma unroll
        for (int j = 0; j < 4; ++j) acc[i][j] = (f32x4){0.f, 0.f, 0.f, 0.f};

      for (int k0 = 0; k0 < HIDDEN; k0 += 32) {
        __syncthreads();
#pragma unroll
        for (int i = 0; i < 2; ++i) {
          int rr = w * 32 + i * 16;
          gl_lds16(A + (size_t)(rr + srowq) * HIDDEN + k0 + skq, Al + rr * 32);
          gl_lds16(Wfc + (size_t)(n0 + rr + srowq) * HIDDEN + k0 + skq, Bl + rr * 32);
        }
        __syncthreads();

        const u16* ab = Al + (wr * 64 + (lane & 15)) * 32 + (lane >> 4) * 8;
        const u16* bb = Bl + (wc * 64 + (lane & 15)) * 32 + (lane >> 4) * 8;
        s16x8 af[4], bf_[4];
#pragma unroll
        for (int mi = 0; mi < 4; ++mi) af[mi] = *(const s16x8*)(ab + mi * 16 * 32);
#pragma unroll
        for (int ni = 0; ni < 4; ++ni) bf_[ni] = *(const s16x8*)(bb + ni * 16 * 32);
#pragma unroll
        for (int mi = 0; mi < 4; ++mi)
#pragma unroll
          for (int ni = 0; ni < 4; ++ni)
            acc[mi][ni] = __builtin_amdgcn_mfma_f32_16x16x32_bf16(af[mi], bf_[ni], acc[mi][ni], 0, 0, 0);
      }

      int rbase = (lane >> 4) * 4;
      int colf = lane & 15;
#pragma unroll
      for (int mi = 0; mi < 4; ++mi) {
        int mbase = wr * 64 + mi * 16 + rbase;   // batch row b
#pragma unroll
        for (int ni = 0; ni < 4; ++ni) {
          int n = n0 + wc * 64 + ni * 16 + colf;
          if (n < VOCAB) {
            float bv = b_fc[n];
#pragma unroll
            for (int reg = 0; reg < 4; ++reg)
              out[(size_t)(mbase + reg) * (TSTEPS * VOCAB) + (size_t)t * VOCAB + n] =
                  acc[mi][ni][reg] + bv;
          }
        }
      }
    }
  }
}

// ---------------------------------------------------------------------------
extern "C" void kernel_launch(void* const* d_in, const int* in_sizes, int n_in,
                              void* d_out, int out_size, void* d_ws, size_t ws_size,
                              hipStream_t stream) {
  const float* features = (const float*)d_in[0];
  const int*   captions = (const int*)d_in[1];
  const float* emb      = (const float*)d_in[2];
  const float* W_ft     = (const float*)d_in[3];
  const float* b_ft     = (const float*)d_in[4];
  GatePtrs p;
  p.W[0] = (const float*)d_in[5];  p.U[0] = (const float*)d_in[6];  p.b[0] = (const float*)d_in[7];
  p.W[1] = (const float*)d_in[8];  p.U[1] = (const float*)d_in[9];  p.b[1] = (const float*)d_in[10];
  p.W[2] = (const float*)d_in[11]; p.U[2] = (const float*)d_in[12]; p.b[2] = (const float*)d_in[13];
  p.W[3] = (const float*)d_in[14]; p.U[3] = (const float*)d_in[15]; p.b[3] = (const float*)d_in[16];
  const float* W_fc = (const float*)d_in[17];
  const float* b_fc = (const float*)d_in[18];
  float* out = (float*)d_out;

  // workspace carve-up (bytes)
  char* ws = (char*)d_ws;
  u16*      feats_bf  = (u16*)(ws + 0);          // 128*256*2 = 64 KB
  u16*      X_emb     = (u16*)(ws + 131072);     // 4096*256*2 = 2 MB
  float*    gfeats    = (float*)(ws + 2228224);  // 128*2048*4 = 1 MB
  u16*      WcatT     = (u16*)(ws + 4325376);    // 2 MB
  u16*      UcatT     = (u16*)(ws + 6422528);    // 2 MB
  float*    bcat      = (float*)(ws + 8519680);  // 8 KB
  u16*      Wfc_bf    = (u16*)(ws + 8527872);    // 10112*512*2
  float*    gates_pre = (float*)(ws + 18882560); // 33.55 MB
  int*      flags     = (int*)(ws + 52436992);   // 64 ints + ticket
  int*      ticket    = flags + 64;
  unsigned* hx        = (unsigned*)(ws + 52846592); // 4 MB ([t*128+b][512] bf16)

  hipMemsetAsync(flags, 0, 512, stream);

  // merged prep: feats_bf + W/U transpose + X_emb gather + Wfc cast + bcat
  k_prep_all<<<1664 + (WFC_PAD * HIDDEN / 4 + 255) / 256, 256, 0, stream>>>(
      p, features, W_ft, b_ft, W_fc, emb, captions,
      feats_bf, WcatT, UcatT, bcat, Wfc_bf, X_emb);

  // gfeats[b][n] = feats_bf[b] @ WcatT[n][256:512]^T + bcat[n]   (K=256)
  k_gemm_bt<<<dim3(16, 1), 256, 0, stream>>>(
      feats_bf, 256, WcatT + 256, 512, bcat, nullptr, gfeats, 128, 2048, 256);

  // gates_pre[t*128+b][n] = X_emb @ WcatT[:, :256]^T + gfeats[b][n]  (K=256)
  k_gemm_bt<<<dim3(16, 32), 256, 0, stream>>>(
      X_emb, 256, WcatT, 512, nullptr, gfeats, gates_pre, 4096, 2048, 256);

  // fused: 64 LSTM blocks + 192 final-GEMM workers (out = hx @ Wfc^T + b_fc)
  k_fused<<<256, 256, 0, stream>>>(UcatT, gates_pre, hx, flags, ticket,
                                   Wfc_bf, b_fc, out);
}

// Round 16
// 301.843 us; speedup vs baseline: 1.0719x; 1.0719x over previous
//
#include <hip/hip_runtime.h>
#include <hip/hip_bf16.h>

// Problem constants
#define EMBED    256
#define HIDDEN   512
#define VOCAB    10000
#define WFC_PAD  10112   // 79 * 128, zero-padded rows for gload_lds edge tiles
#define NTILES   79      // WFC_PAD / 128
#define FEAT_DIM 1024
#define BATCH    128
#define NREGS    49
#define TSTEPS   32      // CAPLEN-1

typedef unsigned short u16;
typedef unsigned long long u64;
using f32x4 = __attribute__((ext_vector_type(4))) float;
using s16x8 = __attribute__((ext_vector_type(8))) short;
using u32x4 = __attribute__((ext_vector_type(4))) unsigned;

__device__ __forceinline__ u16 f2bf(float f) {
  __hip_bfloat16 h = __float2bfloat16(f);
  return *reinterpret_cast<u16*>(&h);
}
__device__ __forceinline__ float sig_(float x) {
  return 1.0f / (1.0f + __expf(-x));
}
__device__ __forceinline__ float tanh_(float x) {
  x = fminf(fmaxf(x, -15.f), 15.f);
  float e = __expf(2.f * x);
  return (e - 1.f) / (e + 1.f);
}
// async global->LDS, 16B per lane; LDS dest is wave-uniform base + lane*16
__device__ __forceinline__ void gl_lds16(const u16* g, u16* l) {
  __builtin_amdgcn_global_load_lds(
      (const __attribute__((address_space(1))) unsigned*)g,
      (__attribute__((address_space(3))) unsigned*)l, 16, 0, 0);
}

struct GatePtrs {
  const float* W[4];
  const float* U[4];
  const float* b[4];
};

// ---------------------------------------------------------------------------
// Kernel 1 (merged prep, round-15 proven): blocks 0..127 = feats_bf;
// 128..639 = W/U transpose+cast; 640..1663 = X_emb gather; 1664.. = Wfc cast
// (padded) + bcat.
// ---------------------------------------------------------------------------
__global__ __launch_bounds__(256)
void k_prep_all(GatePtrs p, const float* __restrict__ features,
                const float* __restrict__ W_ft, const float* __restrict__ b_ft,
                const float* __restrict__ W_fc, const float* __restrict__ emb,
                const int* __restrict__ captions,
                u16* __restrict__ feats_bf, u16* __restrict__ WcatT,
                u16* __restrict__ UcatT, float* __restrict__ bcat,
                u16* __restrict__ Wfc_bf, u16* __restrict__ X_emb) {
  __shared__ float sh[64 * 65];
  int bid = blockIdx.x, tid = threadIdx.x;

  if (bid < 128) {
    // ---- feats: mean over regions, project, cast to bf16 ----
    float* mean = sh;
    int b = bid;
    const float* fb = features + (size_t)b * NREGS * FEAT_DIM;
    for (int d = tid; d < FEAT_DIM; d += 256) {
      float s = 0.f;
      for (int r = 0; r < NREGS; ++r) s += fb[r * FEAT_DIM + d];
      mean[d] = s * (1.0f / 49.0f);
    }
    __syncthreads();
    const float* w = W_ft + (size_t)tid * FEAT_DIM;
    float acc = b_ft[tid];
#pragma unroll 4
    for (int d = 0; d < FEAT_DIM; d += 4) {
      float4 m4 = *(const float4*)&mean[d];
      float4 w4 = *(const float4*)&w[d];
      acc += m4.x * w4.x + m4.y * w4.y + m4.z * w4.z + m4.w * w4.w;
    }
    feats_bf[b * EMBED + tid] = f2bf(acc);
  } else if (bid < 640) {
    // ---- W/U transpose + cast ----
    int idx = bid - 128;
    int z = idx >> 8;
    int rem = idx & 255;
    int g = rem >> 6;
    int x = rem & 63;
    float (*tile)[65] = (float(*)[65])sh;
    const float* src = z ? p.U[g] : p.W[g];
    u16* dst = z ? UcatT : WcatT;
    int tj = (x & 7) * 64;
    int tk = (x >> 3) * 64;
    int tx = tid & 63, ty = tid >> 6;
#pragma unroll
    for (int i = 0; i < 16; ++i)
      tile[ty + 4 * i][tx] = src[(size_t)(tk + ty + 4 * i) * HIDDEN + tj + tx];
    __syncthreads();
#pragma unroll
    for (int i = 0; i < 16; ++i)
      dst[(size_t)(g * 512 + tj + ty + 4 * i) * 512 + tk + tx] = f2bf(tile[tx][ty + 4 * i]);
  } else if (bid < 1664) {
    // ---- X_emb gather: row r = t*128+b -> emb[captions[b][t]][0..255] ----
    int idx = (bid - 640) * 256 + tid;   // [0, 4096*64)
    int r = idx >> 6, c4 = (idx & 63) * 4;
    int t = r >> 7, b = r & 127;
    int tok = captions[b * 33 + t];
    float4 v = *(const float4*)(emb + (size_t)tok * EMBED + c4);
    ushort4 o;
    o.x = f2bf(v.x); o.y = f2bf(v.y); o.z = f2bf(v.z); o.w = f2bf(v.w);
    *(ushort4*)(X_emb + (size_t)r * EMBED + c4) = o;
  } else {
    // ---- Wfc cast (zero-padded) + bcat ----
    int idx = (bid - 1664) * 256 + tid;
    if (idx < WFC_PAD * HIDDEN / 4) {
      size_t e0 = (size_t)idx * 4;
      ushort4 o;
      if (e0 < (size_t)VOCAB * HIDDEN) {
        float4 v = *(const float4*)(W_fc + e0);
        o.x = f2bf(v.x); o.y = f2bf(v.y); o.z = f2bf(v.z); o.w = f2bf(v.w);
      } else {
        o.x = o.y = o.z = o.w = 0;
      }
      *(ushort4*)(Wfc_bf + e0) = o;
    }
    if (idx < 4 * HIDDEN) bcat[idx] = p.b[idx >> 9][idx & 511];
  }
}

// ---------------------------------------------------------------------------
// Kernel 2: gates GEMM with split A-source (the one new thing this round):
// gates_pre[t*128+b][n] = [X_emb | feats_bf] @ WcatT^T + bcat,  K=512.
// Each 128-row m-tile is one t-block, so row-in-tile == batch index b:
// staging reads X_emb[(m0+row)*256 + k] for k<256 and feats_bf[row*256 +
// (k-256)] for k>=256 (both lda=256, identical tile-row indexing). No
// materialized X, no extra launch. m97 structure otherwise unchanged.
// ---------------------------------------------------------------------------
__global__ __launch_bounds__(256)
void k_gates_gemm(const u16* __restrict__ X_emb, const u16* __restrict__ feats_bf,
                  const u16* __restrict__ WcatT, const float* __restrict__ bcat,
                  float* __restrict__ C) {
  __shared__ u16 Al[128 * 32];
  __shared__ u16 Bl[128 * 32];
  const int M = 4096, N = 2048, K = 512;
  int tid = threadIdx.x;
  int lane = tid & 63;
  int w = tid >> 6;
  int wr = w & 1, wc = w >> 1;

  // bijective XCD swizzle (m204)
  int Mtiles = gridDim.y, Ntiles = gridDim.x;
  int nwg = Mtiles * Ntiles;
  int id = blockIdx.y * Ntiles + blockIdx.x;
  int q = nwg >> 3, r = nwg & 7;
  int xcd = id & 7, pos = id >> 3;
  int wg = (xcd < r ? xcd * (q + 1) : r * (q + 1) + (xcd - r) * q) + pos;
  int m0 = (wg % Mtiles) * 128;
  int n0 = (wg / Mtiles) * 128;

  f32x4 acc[4][4];
#pragma unroll
  for (int i = 0; i < 4; ++i)
#pragma unroll
    for (int j = 0; j < 4; ++j) acc[i][j] = (f32x4){0.f, 0.f, 0.f, 0.f};

  int srowq = lane >> 2;
  int skq   = (lane & 3) * 8;

  for (int k0 = 0; k0 < K; k0 += 32) {
    __syncthreads();
#pragma unroll
    for (int i = 0; i < 2; ++i) {
      int rr = w * 32 + i * 16;
      // split A source: emb half vs broadcast feats half (row-in-tile = b)
      const u16* asrc = (k0 < 256)
          ? X_emb + (size_t)(m0 + rr + srowq) * 256 + k0 + skq
          : feats_bf + (size_t)(rr + srowq) * 256 + (k0 - 256) + skq;
      gl_lds16(asrc, Al + rr * 32);
      gl_lds16(WcatT + (size_t)(n0 + rr + srowq) * 512 + k0 + skq, Bl + rr * 32);
    }
    __syncthreads();

    const u16* ab = Al + (wr * 64 + (lane & 15)) * 32 + (lane >> 4) * 8;
    const u16* bb = Bl + (wc * 64 + (lane & 15)) * 32 + (lane >> 4) * 8;
    s16x8 af[4], bf_[4];
#pragma unroll
    for (int mi = 0; mi < 4; ++mi) af[mi] = *(const s16x8*)(ab + mi * 16 * 32);
#pragma unroll
    for (int ni = 0; ni < 4; ++ni) bf_[ni] = *(const s16x8*)(bb + ni * 16 * 32);
#pragma unroll
    for (int mi = 0; mi < 4; ++mi)
#pragma unroll
      for (int ni = 0; ni < 4; ++ni)
        acc[mi][ni] = __builtin_amdgcn_mfma_f32_16x16x32_bf16(af[mi], bf_[ni], acc[mi][ni], 0, 0, 0);
  }

  int rbase = (lane >> 4) * 4;
  int colf = lane & 15;
#pragma unroll
  for (int mi = 0; mi < 4; ++mi) {
    int mbase = m0 + wr * 64 + mi * 16 + rbase;
#pragma unroll
    for (int ni = 0; ni < 4; ++ni) {
      int n = n0 + wc * 64 + ni * 16 + colf;
      float bv = bcat[n];
#pragma unroll
      for (int reg = 0; reg < 4; ++reg)
        C[(size_t)(mbase + reg) * N + n] = acc[mi][ni][reg] + bv;
    }
  }
}

// ---------------------------------------------------------------------------
// Kernel 3 (FUSED — round-13 proven, byte-identical): blocks 0..63 = LSTM
// (block flags, __syncthreads drain, tid0 flag store, gpv prefetch after
// flag); blocks 64..255 = final-GEMM workers (t-major tickets, wave0 poll).
// ---------------------------------------------------------------------------
#define USTR 520

__global__ __launch_bounds__(256, 1)
void k_fused(const u16* __restrict__ UcatT, const float* __restrict__ gates_pre,
             unsigned* __restrict__ hx, int* __restrict__ flags, int* __restrict__ ticket,
             const u16* __restrict__ Wfc, const float* __restrict__ b_fc,
             float* __restrict__ out) {
  __shared__ u16 SH[128 * USTR];   // lstm: Ul (133,120B); workers: Al|Bl (16KB)
  __shared__ int tickLds;
  int tid = threadIdx.x;
  int lane = tid & 63;
  int w = tid >> 6;

  if (blockIdx.x < 64) {
    // ======================= LSTM path =======================
    u16* Ul = SH;
    int wr = w & 1, wj = w >> 1;
    int mg = blockIdx.x >> 4;
    int jb = blockIdx.x & 15;
    int b0 = mg * 32;
    int j0 = jb * 32;

    for (int i = tid; i < 128 * 64; i += 256) {
      int row = i >> 6;
      int kc = (i & 63) * 8;
      int gr = ((row >> 5) << 9) + j0 + (row & 31);
      uint4 v = *(const uint4*)(UcatT + (size_t)gr * 512 + kc);
      *(uint4*)(Ul + row * USTR + kc) = v;
    }
    __syncthreads();

    int jloc = wj * 16 + (lane & 15);
    int jj = j0 + jloc;
    int rb = wr * 16 + (lane >> 4) * 4;
    int arow = b0 + wr * 16 + (lane & 15);
    const u16* ubase = Ul + (size_t)jloc * USTR + (lane >> 4) * 8;
    int* myflag = flags + mg * 16 + jb;
    const int* pollp = flags + mg * 16 + (lane & 15);

    float c[4] = {0.f, 0.f, 0.f, 0.f};
    float gpv[16];

#pragma unroll
    for (int reg = 0; reg < 4; ++reg)
#pragma unroll
      for (int gi = 0; gi < 4; ++gi)
        gpv[reg * 4 + gi] = gates_pre[((size_t)(b0 + rb + reg)) * 2048 + gi * 512 + jj];

#pragma unroll 1
    for (int t = 0; t < TSTEPS; ++t) {
      f32x4 acc[4];
#pragma unroll
      for (int gi = 0; gi < 4; ++gi) acc[gi] = (f32x4){0.f, 0.f, 0.f, 0.f};

      if (t > 0) {
        // poll the 16 block-flags of this m-group (one 64B line);
        // first round's vmcnt(0) also drains our gpv prefetch (intended).
        int fv;
        do {
          asm volatile(
              "global_load_dword %0, %1, off sc0 sc1\n\t"
              "s_waitcnt vmcnt(0)"
              : "=v"(fv) : "v"(pollp) : "memory");
        } while (!__all(fv >= t));

        const u16* hp = (const u16*)hx + ((size_t)(t - 1) * 128 + arow) * 512 + (lane >> 4) * 8;
        u32x4 f[16];
        asm volatile(
            "global_load_dwordx4 %0, %4, off sc0 sc1\n\t"
            "global_load_dwordx4 %1, %4, off offset:64 sc0 sc1\n\t"
            "global_load_dwordx4 %2, %4, off offset:128 sc0 sc1\n\t"
            "global_load_dwordx4 %3, %4, off offset:192 sc0 sc1"
            : "=&v"(f[0]), "=&v"(f[1]), "=&v"(f[2]), "=&v"(f[3])
            : "v"(hp) : "memory");
        asm volatile(
            "global_load_dwordx4 %0, %4, off offset:256 sc0 sc1\n\t"
            "global_load_dwordx4 %1, %4, off offset:320 sc0 sc1\n\t"
            "global_load_dwordx4 %2, %4, off offset:384 sc0 sc1\n\t"
            "global_load_dwordx4 %3, %4, off offset:448 sc0 sc1"
            : "=&v"(f[4]), "=&v"(f[5]), "=&v"(f[6]), "=&v"(f[7])
            : "v"(hp) : "memory");
        asm volatile(
            "global_load_dwordx4 %0, %4, off offset:512 sc0 sc1\n\t"
            "global_load_dwordx4 %1, %4, off offset:576 sc0 sc1\n\t"
            "global_load_dwordx4 %2, %4, off offset:640 sc0 sc1\n\t"
            "global_load_dwordx4 %3, %4, off offset:704 sc0 sc1"
            : "=&v"(f[8]), "=&v"(f[9]), "=&v"(f[10]), "=&v"(f[11])
            : "v"(hp) : "memory");
        asm volatile(
            "global_load_dwordx4 %0, %4, off offset:768 sc0 sc1\n\t"
            "global_load_dwordx4 %1, %4, off offset:832 sc0 sc1\n\t"
            "global_load_dwordx4 %2, %4, off offset:896 sc0 sc1\n\t"
            "global_load_dwordx4 %3, %4, off offset:960 sc0 sc1\n\t"
            "s_waitcnt vmcnt(0)"
            : "=&v"(f[12]), "=&v"(f[13]), "=&v"(f[14]), "=&v"(f[15])
            : "v"(hp) : "memory");
        __builtin_amdgcn_sched_barrier(0);

#pragma unroll
        for (int kk = 0; kk < 16; ++kk) {
          s16x8 af = __builtin_bit_cast(s16x8, f[kk]);
#pragma unroll
          for (int gi = 0; gi < 4; ++gi) {
            s16x8 bf_ = *(const s16x8*)(ubase + (size_t)gi * 32 * USTR + kk * 32);
            acc[gi] = __builtin_amdgcn_mfma_f32_16x16x32_bf16(af, bf_, acc[gi], 0, 0, 0);
          }
        }
      }

      // cell epilogue (registers), publish h
#pragma unroll
      for (int reg = 0; reg < 4; ++reg) {
        float pi = acc[0][reg] + gpv[reg * 4 + 0];
        float pf = acc[1][reg] + gpv[reg * 4 + 1];
        float pg = acc[2][reg] + gpv[reg * 4 + 2];
        float po = acc[3][reg] + gpv[reg * 4 + 3];
        float iv = sig_(pi), fv2 = sig_(pf), gv = tanh_(pg), ov = sig_(po);
        float cn = fv2 * c[reg] + iv * gv;
        c[reg] = cn;
        float hn = ov * tanh_(cn);
        u16 hb = f2bf(hn);
        unsigned pv = hb;
        unsigned nv = __shfl_down(pv, 1);
        if ((lane & 1) == 0) {
          unsigned packed = pv | (nv << 16);
          unsigned* dst = hx + ((size_t)t * 128 + b0 + rb + reg) * 256 + (jj >> 1);
          asm volatile("global_store_dword %0, %1, off sc0 sc1"
                       :: "v"(dst), "v"(packed) : "memory");
        }
      }

      // barrier drains all waves' h stores -> tid0 publishes the block flag
      __syncthreads();
      if (tid == 0) {
        int fl = t + 1;
        asm volatile("global_store_dword %0, %1, off sc0 sc1"
                     :: "v"(myflag), "v"(fl) : "memory");
      }

      // gpv prefetch AFTER the flag — off the inter-block critical path;
      // its latency is absorbed by the next poll round's vmcnt(0).
      if (t < TSTEPS - 1) {
#pragma unroll
        for (int reg = 0; reg < 4; ++reg)
#pragma unroll
          for (int gi = 0; gi < 4; ++gi)
            gpv[reg * 4 + gi] =
                gates_pre[((size_t)(t + 1) * 128 + b0 + rb + reg) * 2048 + gi * 512 + jj];
      }
    }
  } else {
    // ======================= GEMM worker path =======================
    u16* Al = SH;
    u16* Bl = SH + 128 * 32;
    int wr = w & 1, wc = w >> 1;
    int srowq = lane >> 2;
    int skq   = (lane & 3) * 8;
    const u16* hx16 = (const u16*)hx;

    for (;;) {
      if (tid == 0)
        tickLds = __hip_atomic_fetch_add(ticket, 1, __ATOMIC_RELAXED, __HIP_MEMORY_SCOPE_AGENT);
      __syncthreads();
      int T = tickLds;
      if (T >= TSTEPS * NTILES) break;
      int t = T / NTILES, nt = T % NTILES;

      // gate: all 64 step-flags >= t+1 — only wave 0 polls, barrier broadcasts
      if (w == 0) {
        const int* fp = flags + lane;
        for (;;) {
          int fv;
          asm volatile(
              "global_load_dword %0, %1, off sc0 sc1\n\t"
              "s_waitcnt vmcnt(0)"
              : "=v"(fv) : "v"(fp) : "memory");
          if (__all(fv >= t + 1)) break;
          __builtin_amdgcn_s_sleep(64);
        }
      }
      __syncthreads();

      const u16* A = hx16 + (size_t)t * 128 * 512;
      int n0 = nt * 128;

      f32x4 acc[4][4];
#pragma unroll
      for (int i = 0; i < 4; ++i)
#pragma unroll
        for (int j = 0; j < 4; ++j) acc[i][j] = (f32x4){0.f, 0.f, 0.f, 0.f};

      for (int k0 = 0; k0 < HIDDEN; k0 += 32) {
        __syncthreads();
#pragma unroll
        for (int i = 0; i < 2; ++i) {
          int rr = w * 32 + i * 16;
          gl_lds16(A + (size_t)(rr + srowq) * HIDDEN + k0 + skq, Al + rr * 32);
          gl_lds16(Wfc + (size_t)(n0 + rr + srowq) * HIDDEN + k0 + skq, Bl + rr * 32);
        }
        __syncthreads();

        const u16* ab = Al + (wr * 64 + (lane & 15)) * 32 + (lane >> 4) * 8;
        const u16* bb = Bl + (wc * 64 + (lane & 15)) * 32 + (lane >> 4) * 8;
        s16x8 af[4], bf_[4];
#pragma unroll
        for (int mi = 0; mi < 4; ++mi) af[mi] = *(const s16x8*)(ab + mi * 16 * 32);
#pragma unroll
        for (int ni = 0; ni < 4; ++ni) bf_[ni] = *(const s16x8*)(bb + ni * 16 * 32);
#pragma unroll
        for (int mi = 0; mi < 4; ++mi)
#pragma unroll
          for (int ni = 0; ni < 4; ++ni)
            acc[mi][ni] = __builtin_amdgcn_mfma_f32_16x16x32_bf16(af[mi], bf_[ni], acc[mi][ni], 0, 0, 0);
      }

      int rbase = (lane >> 4) * 4;
      int colf = lane & 15;
#pragma unroll
      for (int mi = 0; mi < 4; ++mi) {
        int mbase = wr * 64 + mi * 16 + rbase;   // batch row b
#pragma unroll
        for (int ni = 0; ni < 4; ++ni) {
          int n = n0 + wc * 64 + ni * 16 + colf;
          if (n < VOCAB) {
            float bv = b_fc[n];
#pragma unroll
            for (int reg = 0; reg < 4; ++reg)
              out[(size_t)(mbase + reg) * (TSTEPS * VOCAB) + (size_t)t * VOCAB + n] =
                  acc[mi][ni][reg] + bv;
          }
        }
      }
    }
  }
}

// ---------------------------------------------------------------------------
extern "C" void kernel_launch(void* const* d_in, const int* in_sizes, int n_in,
                              void* d_out, int out_size, void* d_ws, size_t ws_size,
                              hipStream_t stream) {
  const float* features = (const float*)d_in[0];
  const int*   captions = (const int*)d_in[1];
  const float* emb      = (const float*)d_in[2];
  const float* W_ft     = (const float*)d_in[3];
  const float* b_ft     = (const float*)d_in[4];
  GatePtrs p;
  p.W[0] = (const float*)d_in[5];  p.U[0] = (const float*)d_in[6];  p.b[0] = (const float*)d_in[7];
  p.W[1] = (const float*)d_in[8];  p.U[1] = (const float*)d_in[9];  p.b[1] = (const float*)d_in[10];
  p.W[2] = (const float*)d_in[11]; p.U[2] = (const float*)d_in[12]; p.b[2] = (const float*)d_in[13];
  p.W[3] = (const float*)d_in[14]; p.U[3] = (const float*)d_in[15]; p.b[3] = (const float*)d_in[16];
  const float* W_fc = (const float*)d_in[17];
  const float* b_fc = (const float*)d_in[18];
  float* out = (float*)d_out;

  // workspace carve-up (bytes)
  char* ws = (char*)d_ws;
  u16*      feats_bf  = (u16*)(ws + 0);          // 128*256*2 = 64 KB
  u16*      X_emb     = (u16*)(ws + 131072);     // 4096*256*2 = 2 MB
  u16*      WcatT     = (u16*)(ws + 4325376);    // 2 MB
  u16*      UcatT     = (u16*)(ws + 6422528);    // 2 MB
  float*    bcat      = (float*)(ws + 8519680);  // 8 KB
  u16*      Wfc_bf    = (u16*)(ws + 8527872);    // 10112*512*2
  float*    gates_pre = (float*)(ws + 18882560); // 33.55 MB
  int*      flags     = (int*)(ws + 52436992);   // 64 ints + ticket
  int*      ticket    = flags + 64;
  unsigned* hx        = (unsigned*)(ws + 52846592); // 4 MB ([t*128+b][512] bf16)

  hipMemsetAsync(flags, 0, 512, stream);

  // merged prep: feats_bf + W/U transpose + X_emb gather + Wfc cast + bcat
  k_prep_all<<<1664 + (WFC_PAD * HIDDEN / 4 + 255) / 256, 256, 0, stream>>>(
      p, features, W_ft, b_ft, W_fc, emb, captions,
      feats_bf, WcatT, UcatT, bcat, Wfc_bf, X_emb);

  // gates_pre = [X_emb | feats_bf] @ WcatT^T + bcat   (split-source A, K=512)
  k_gates_gemm<<<dim3(16, 32), 256, 0, stream>>>(
      X_emb, feats_bf, WcatT, bcat, gates_pre);

  // fused: 64 LSTM blocks + 192 final-GEMM workers (out = hx @ Wfc^T + b_fc)
  k_fused<<<256, 256, 0, stream>>>(UcatT, gates_pre, hx, flags, ticket,
                                   Wfc_bf, b_fc, out);
}